// Round 6
// baseline (268.312 us; speedup 1.0000x reference)
//
#include <hip/hip_runtime.h>

#define HH 512
#define WW 512
#define HO 502
#define WO 502
#define KS 11
#define OTH 32                 // v-rows per tile
#define RPT 4                  // v-rows per thread (8 groups of 32 lanes)
#define NR  (RPT + KS - 1)     // 14 input rows per thread
#define OTW 21                 // output cols per tile
#define VW  31                 // v-cols = OTW + KS - 1
#define RS  33                 // row stride (odd -> conflict-free)
#define CHS (VW * RS)          // 1023 dwords per channel
#define CPT 3                  // output cols per thread in phase 2
#define NPOS (CPT + KS - 1)    // 13 tap positions

// symmetric gaussian lookup, k compile-time
#define GW(k) g[(k) < 6 ? (k) : 10 - (k)]

__global__ __launch_bounds__(256, 8)   // min 8 waves/EU -> VGPR cap 64 -> 8 blocks/CU
void ssim_sep_kernel(
    const float* __restrict__ img1, const float* __restrict__ img2,
    const float* __restrict__ win, double* __restrict__ acc)
{
    __shared__ float vbuf[5 * CHS];    // 20,460 B -> 8 blocks/CU (160 KiB / 8 = 20,480)

    const int tid = threadIdx.x;
    const int tile_c0 = blockIdx.x * OTW;
    const int tile_r0 = blockIdx.y * OTH;
    const size_t base = (size_t)blockIdx.z * (HH * WW);

    // 1-D gaussian from separable 2-D window: g[k] = w[5][k]/sqrt(w[5][5]); symmetric
    float g[6];
    {
        double inv = 1.0 / sqrt((double)win[5 * KS + 5]);
        #pragma unroll
        for (int k = 0; k < 6; ++k)
            g[k] = (float)((double)win[5 * KS + k] * inv);
    }

    // ---------- phase 1: vertical conv, global -> regs -> LDS (transposed) ----------
    {
        const int lane = tid & 31;          // v column
        const int j0 = (tid >> 5) * RPT;    // first v-row owned (0,4,...,28)
        int gc = tile_c0 + lane;
        if (gc > WW - 1) gc = WW - 1;       // clamped cols feed only discarded outputs

        const float* p1 = img1 + base;
        const float* p2 = img2 + base;

        float a[NR], b[NR];
        #pragma unroll
        for (int ri = 0; ri < NR; ++ri) {
            int gr = tile_r0 + j0 + ri;
            if (gr > HH - 1) gr = HH - 1;   // clamped rows feed only discarded outputs
            const size_t ro = (size_t)gr * WW;
            a[ri] = p1[ro + gc];
            b[ri] = p2[ro + gc];
        }

        float accv[5][RPT];
        #pragma unroll
        for (int ch = 0; ch < 5; ++ch)
            #pragma unroll
            for (int j = 0; j < RPT; ++j) accv[ch][j] = 0.f;

        #pragma unroll
        for (int ri = 0; ri < NR; ++ri) {
            float av = a[ri], bv = b[ri];
            float aa = av * av, bb = bv * bv, ab = av * bv;
            #pragma unroll
            for (int j = 0; j < RPT; ++j) {
                int k = ri - j;
                if (k >= 0 && k < KS) {     // folds at compile time
                    float w = GW(k);
                    accv[0][j] += w * av;
                    accv[1][j] += w * bv;
                    accv[2][j] += w * aa;
                    accv[3][j] += w * bb;
                    accv[4][j] += w * ab;
                }
            }
        }
        if (lane < VW) {
            const int cb = lane * RS + j0;
            #pragma unroll
            for (int ch = 0; ch < 5; ++ch)
                #pragma unroll
                for (int j = 0; j < RPT; ++j)
                    vbuf[ch * CHS + cb + j] = accv[ch][j];
        }
    }
    __syncthreads();

    // ---------- phase 2: horizontal conv + SSIM ----------
    float lsum = 0.f;
    {
        const int r  = tid & 31;            // output row in tile
        const int cg = tid >> 5;            // col group 0..7
        const int c0 = cg * CPT;            // 0,3,...,21
        // cg==7 (cols 21..23) is fully masked below; alias its reads to cg==6's
        // window so ds_read offsets stay immediate and in-bounds.
        const int c0r = (c0 > VW - NPOS) ? (VW - NPOS) : c0;   // <= 18

        float acco[5][CPT];
        #pragma unroll
        for (int ch = 0; ch < 5; ++ch)
            #pragma unroll
            for (int j = 0; j < CPT; ++j) acco[ch][j] = 0.f;

        #pragma unroll
        for (int ch = 0; ch < 5; ++ch) {
            const float* vp = &vbuf[ch * CHS + c0r * RS + r];
            #pragma unroll
            for (int i = 0; i < NPOS; ++i) {          // 13 positions
                float v = vp[i * RS];                 // lanes r=0..31 -> consecutive addrs
                #pragma unroll
                for (int j = 0; j < CPT; ++j) {
                    int k = i - j;
                    if (k >= 0 && k < KS)             // folds at compile time
                        acco[ch][j] += GW(k) * v;
                }
            }
        }

        const float c1 = 1e-4f, c2 = 9e-4f;           // L = 1 for [0,1) inputs
        const int orow = tile_r0 + r;
        #pragma unroll
        for (int j = 0; j < CPT; ++j) {
            int lc = c0 + j, ocol = tile_c0 + lc;
            if (lc < OTW && ocol < WO && orow < HO) {
                float mu1 = acco[0][j], mu2 = acco[1][j];
                float e11 = acco[2][j], e22 = acco[3][j], e12 = acco[4][j];
                float mu1s = mu1 * mu1, mu2s = mu2 * mu2, mu12 = mu1 * mu2;
                float sg1 = e11 - mu1s, sg2 = e22 - mu2s, sg12 = e12 - mu12;
                float num = (2.f * mu12 + c1) * (2.f * sg12 + c2);
                float den = (mu1s + mu2s + c1) * (sg1 + sg2 + c2);
                lsum += num * __builtin_amdgcn_rcpf(den);
            }
        }
    }

    // ---------- reduction ----------
    #pragma unroll
    for (int off = 32; off; off >>= 1)
        lsum += __shfl_down(lsum, off, 64);
    __syncthreads();                      // vbuf reads done -> reuse for partials
    if ((tid & 63) == 0) vbuf[tid >> 6] = lsum;
    __syncthreads();
    if (tid == 0) {
        double t = (double)vbuf[0] + (double)vbuf[1] +
                   (double)vbuf[2] + (double)vbuf[3];
        atomicAdd(acc, t);
    }
}

__global__ void ssim_finalize(const double* __restrict__ acc,
                              float* __restrict__ out)
{
    out[0] = (float)(acc[0] / (double)(16LL * 3LL * (long long)HO * (long long)WO));
}

extern "C" void kernel_launch(void* const* d_in, const int* in_sizes, int n_in,
                              void* d_out, int out_size, void* d_ws, size_t ws_size,
                              hipStream_t stream) {
    const float* img1 = (const float*)d_in[0];
    const float* img2 = (const float*)d_in[1];
    const float* win  = (const float*)d_in[2];  // (3,1,11,11); channels identical
    float* out = (float*)d_out;
    double* acc = (double*)d_ws;

    hipMemsetAsync(acc, 0, sizeof(double), stream);

    dim3 grid((WO + OTW - 1) / OTW, (HO + OTH - 1) / OTH, 16 * 3);
    ssim_sep_kernel<<<grid, 256, 0, stream>>>(img1, img2, win, acc);
    ssim_finalize<<<1, 1, 0, stream>>>(acc, out);
}

// Round 7
// 239.436 us; speedup vs baseline: 1.1206x; 1.1206x over previous
//
#include <hip/hip_runtime.h>

#define HH 512
#define WW 512
#define HO 502
#define WO 502
#define KS 11
#define OTH 32                 // v-rows per tile
#define RPT 4                  // v-rows per thread (8 groups of 32 lanes)
#define NR  (RPT + KS - 1)     // 14 input rows per thread
#define OTW 21                 // output cols per tile
#define VW  31                 // v-cols = OTW + KS - 1
#define RS  33                 // row stride (odd -> conflict-free)
#define CHS (VW * RS)          // 1023 dwords per channel
#define CPT 3                  // output cols per thread in phase 2
#define NPOS (CPT + KS - 1)    // 13 tap positions

// symmetric gaussian lookup, k compile-time
#define GW(k) g[(k) < 6 ? (k) : 10 - (k)]

__global__ __launch_bounds__(256)      // natural VGPR allocation (target: <=64)
void ssim_sep_kernel(
    const float* __restrict__ img1, const float* __restrict__ img2,
    const float* __restrict__ win, double* __restrict__ acc)
{
    __shared__ float vbuf[5 * CHS];    // 20,460 B -> 8 blocks/CU (160 KiB / 8 = 20,480)

    const int tid = threadIdx.x;
    const int tile_c0 = blockIdx.x * OTW;
    const int tile_r0 = blockIdx.y * OTH;
    const size_t base = (size_t)blockIdx.z * (HH * WW);

    // 1-D gaussian from separable 2-D window: g[k] = w[5][k]/sqrt(w[5][5]); symmetric
    float g[6];
    {
        double inv = 1.0 / sqrt((double)win[5 * KS + 5]);
        #pragma unroll
        for (int k = 0; k < 6; ++k)
            g[k] = (float)((double)win[5 * KS + k] * inv);
    }

    // ---------- phase 1: vertical conv, global -> regs -> LDS (transposed) ----------
    {
        const int lane = tid & 31;          // v column
        const int j0 = (tid >> 5) * RPT;    // first v-row owned (0,4,...,28)
        int gc = tile_c0 + lane;
        if (gc > WW - 1) gc = WW - 1;       // clamped cols feed only discarded outputs

        const float* p1 = img1 + base;
        const float* p2 = img2 + base;

        float a[NR], b[NR];
        #pragma unroll
        for (int ri = 0; ri < NR; ++ri) {
            int gr = tile_r0 + j0 + ri;
            if (gr > HH - 1) gr = HH - 1;   // clamped rows feed only discarded outputs
            const size_t ro = (size_t)gr * WW;
            a[ri] = p1[ro + gc];
            b[ri] = p2[ro + gc];
        }

        float accv[5][RPT];
        #pragma unroll
        for (int ch = 0; ch < 5; ++ch)
            #pragma unroll
            for (int j = 0; j < RPT; ++j) accv[ch][j] = 0.f;

        #pragma unroll
        for (int ri = 0; ri < NR; ++ri) {
            float av = a[ri], bv = b[ri];
            float aa = av * av, bb = bv * bv, ab = av * bv;
            #pragma unroll
            for (int j = 0; j < RPT; ++j) {
                int k = ri - j;
                if (k >= 0 && k < KS) {     // folds at compile time
                    float w = GW(k);
                    accv[0][j] += w * av;
                    accv[1][j] += w * bv;
                    accv[2][j] += w * aa;
                    accv[3][j] += w * bb;
                    accv[4][j] += w * ab;
                }
            }
        }
        if (lane < VW) {
            const int cb = lane * RS + j0;
            #pragma unroll
            for (int ch = 0; ch < 5; ++ch)
                #pragma unroll
                for (int j = 0; j < RPT; ++j)
                    vbuf[ch * CHS + cb + j] = accv[ch][j];
        }
    }
    __syncthreads();

    // ---------- phase 2: horizontal conv + SSIM ----------
    float lsum = 0.f;
    {
        const int r  = tid & 31;            // output row in tile
        const int cg = tid >> 5;            // col group 0..7
        const int c0 = cg * CPT;            // 0,3,...,21
        // cg==7 (cols 21..23) is fully masked below; alias its reads to cg==6's
        // window so ds_read offsets stay immediate and in-bounds.
        const int c0r = (c0 > VW - NPOS) ? (VW - NPOS) : c0;   // <= 18

        float acco[5][CPT];
        #pragma unroll
        for (int ch = 0; ch < 5; ++ch)
            #pragma unroll
            for (int j = 0; j < CPT; ++j) acco[ch][j] = 0.f;

        #pragma unroll
        for (int ch = 0; ch < 5; ++ch) {
            const float* vp = &vbuf[ch * CHS + c0r * RS + r];
            #pragma unroll
            for (int i = 0; i < NPOS; ++i) {          // 13 positions
                float v = vp[i * RS];                 // lanes r=0..31 -> consecutive addrs
                #pragma unroll
                for (int j = 0; j < CPT; ++j) {
                    int k = i - j;
                    if (k >= 0 && k < KS)             // folds at compile time
                        acco[ch][j] += GW(k) * v;
                }
            }
        }

        const float c1 = 1e-4f, c2 = 9e-4f;           // L = 1 for [0,1) inputs
        const int orow = tile_r0 + r;
        #pragma unroll
        for (int j = 0; j < CPT; ++j) {
            int lc = c0 + j, ocol = tile_c0 + lc;
            if (lc < OTW && ocol < WO && orow < HO) {
                float mu1 = acco[0][j], mu2 = acco[1][j];
                float e11 = acco[2][j], e22 = acco[3][j], e12 = acco[4][j];
                float mu1s = mu1 * mu1, mu2s = mu2 * mu2, mu12 = mu1 * mu2;
                float sg1 = e11 - mu1s, sg2 = e22 - mu2s, sg12 = e12 - mu12;
                float num = (2.f * mu12 + c1) * (2.f * sg12 + c2);
                float den = (mu1s + mu2s + c1) * (sg1 + sg2 + c2);
                lsum += num * __builtin_amdgcn_rcpf(den);
            }
        }
    }

    // ---------- reduction ----------
    #pragma unroll
    for (int off = 32; off; off >>= 1)
        lsum += __shfl_down(lsum, off, 64);
    __syncthreads();                      // vbuf reads done -> reuse for partials
    if ((tid & 63) == 0) vbuf[tid >> 6] = lsum;
    __syncthreads();
    if (tid == 0) {
        double t = (double)vbuf[0] + (double)vbuf[1] +
                   (double)vbuf[2] + (double)vbuf[3];
        atomicAdd(acc, t);
    }
}

__global__ void ssim_finalize(const double* __restrict__ acc,
                              float* __restrict__ out)
{
    out[0] = (float)(acc[0] / (double)(16LL * 3LL * (long long)HO * (long long)WO));
}

extern "C" void kernel_launch(void* const* d_in, const int* in_sizes, int n_in,
                              void* d_out, int out_size, void* d_ws, size_t ws_size,
                              hipStream_t stream) {
    const float* img1 = (const float*)d_in[0];
    const float* img2 = (const float*)d_in[1];
    const float* win  = (const float*)d_in[2];  // (3,1,11,11); channels identical
    float* out = (float*)d_out;
    double* acc = (double*)d_ws;

    hipMemsetAsync(acc, 0, sizeof(double), stream);

    dim3 grid((WO + OTW - 1) / OTW, (HO + OTH - 1) / OTH, 16 * 3);
    ssim_sep_kernel<<<grid, 256, 0, stream>>>(img1, img2, win, acc);
    ssim_finalize<<<1, 1, 0, stream>>>(acc, out);
}

// Round 8
// 114.432 us; speedup vs baseline: 2.3447x; 2.0924x over previous
//
#include <hip/hip_runtime.h>

#define HH 512
#define WW 512
#define HO 502
#define WO 502
#define KS 11
#define OTH 32                 // v-rows per tile
#define RPT 8                  // v-rows per thread (4 groups of 64 lanes)
#define NR  (RPT + KS - 1)     // 18 input rows per thread
#define OTW 52                 // output cols per tile
#define VW  62                 // v-cols = OTW + KS - 1
#define RS  33                 // row stride (odd -> conflict-free)
#define CHS (VW * RS)          // 2046 dwords per channel
#define CPT 4                  // output cols per thread in phase 2
#define NPOS (CPT + KS - 1)    // 14 tap positions
#define NCG 13                 // active col groups (13*4 = 52)

typedef float f32x2 __attribute__((ext_vector_type(2)));

// symmetric gaussian lookup, k compile-time
#define GW(k) g[(k) < 6 ? (k) : 10 - (k)]

__global__ __launch_bounds__(256)
void ssim_sep_kernel(
    const float* __restrict__ img1, const float* __restrict__ img2,
    const float* __restrict__ win, double* __restrict__ acc)
{
    __shared__ float vbuf[5 * CHS];    // 40,920 B -> 4 blocks/CU

    const int tid = threadIdx.x;
    const int tile_c0 = blockIdx.x * OTW;
    const int tile_r0 = blockIdx.y * OTH;
    const size_t base = (size_t)blockIdx.z * (HH * WW);

    // 1-D gaussian from separable 2-D window: g[k] = w[5][k]/sqrt(w[5][5]); symmetric
    float g[6];
    {
        double inv = 1.0 / sqrt((double)win[5 * KS + 5]);
        #pragma unroll
        for (int k = 0; k < 6; ++k)
            g[k] = (float)((double)win[5 * KS + k] * inv);
    }

    // ---------- phase 1: vertical conv (channel-paired pk math) ----------
    {
        const int lane = tid & 63;          // v column
        const int j0 = (tid >> 6) * RPT;    // first v-row owned (0,8,16,24)
        int gc = tile_c0 + lane;
        if (gc > WW - 1) gc = WW - 1;       // clamped cols feed only discarded outputs

        const float* p1 = img1 + base;
        const float* p2 = img2 + base;

        f32x2 m12[RPT], ee[RPT];
        float e12[RPT];
        #pragma unroll
        for (int j = 0; j < RPT; ++j) {
            m12[j] = (f32x2){0.f, 0.f};
            ee[j]  = (f32x2){0.f, 0.f};
            e12[j] = 0.f;
        }

        #pragma unroll
        for (int ri = 0; ri < NR; ++ri) {
            int gr = tile_r0 + j0 + ri;
            if (gr > HH - 1) gr = HH - 1;   // clamped rows feed only discarded outputs
            const size_t ro = (size_t)gr * WW;
            float a = p1[ro + gc];
            float b = p2[ro + gc];
            f32x2 xab = {a, b};
            f32x2 xsq = xab * xab;          // pk_mul: {aa, bb}
            float ab = a * b;
            #pragma unroll
            for (int j = 0; j < RPT; ++j) {
                int k = ri - j;
                if (k >= 0 && k < KS) {     // folds at compile time
                    float w = GW(k);
                    m12[j] += w * xab;      // pk_fma
                    ee[j]  += w * xsq;      // pk_fma
                    e12[j] += w * ab;
                }
            }
        }
        if (lane < VW) {
            const int cb = lane * RS + j0;
            #pragma unroll
            for (int j = 0; j < RPT; ++j) {
                vbuf[0 * CHS + cb + j] = m12[j].x;
                vbuf[1 * CHS + cb + j] = m12[j].y;
                vbuf[2 * CHS + cb + j] = ee[j].x;
                vbuf[3 * CHS + cb + j] = ee[j].y;
                vbuf[4 * CHS + cb + j] = e12[j];
            }
        }
    }
    __syncthreads();

    // ---------- phase 2: horizontal conv + SSIM (row-paired pk math) ----------
    float lsum = 0.f;
    {
        const int rp = tid & 15;            // row pair: rows 2rp, 2rp+1
        const int cg = tid >> 4;            // col group 0..15, active < 13
        if (cg < NCG) {
            const int c0 = cg * CPT;        // 0,4,...,48 ; max ci = 48+13 = 61 <= VW-1
            const int rb = 2 * rp;

            f32x2 am[5][CPT];
            #pragma unroll
            for (int ch = 0; ch < 5; ++ch)
                #pragma unroll
                for (int j = 0; j < CPT; ++j) am[ch][j] = (f32x2){0.f, 0.f};

            #pragma unroll
            for (int ch = 0; ch < 5; ++ch) {
                const float* vp = &vbuf[ch * CHS + rb];
                #pragma unroll
                for (int i = 0; i < NPOS; ++i) {
                    const int ci = c0 + i;
                    f32x2 v;
                    v.x = vp[ci * RS];      // lanes rp=0..15 -> even banks, 2-way (free)
                    v.y = vp[ci * RS + 1];
                    #pragma unroll
                    for (int j = 0; j < CPT; ++j) {
                        int k = i - j;
                        if (k >= 0 && k < KS)        // folds at compile time
                            am[ch][j] += GW(k) * v;  // pk_fma
                    }
                }
            }

            const float c1 = 1e-4f, c2 = 9e-4f;      // L = 1 for [0,1) inputs
            const int orow0 = tile_r0 + rb;
            #pragma unroll
            for (int j = 0; j < CPT; ++j) {
                int ocol = tile_c0 + c0 + j;
                if (ocol < WO) {
                    f32x2 mu1 = am[0][j], mu2 = am[1][j];
                    f32x2 e11 = am[2][j], e22 = am[3][j], e12 = am[4][j];
                    f32x2 mu1s = mu1 * mu1, mu2s = mu2 * mu2, mu12 = mu1 * mu2;
                    f32x2 sg1 = e11 - mu1s, sg2 = e22 - mu2s, sg12 = e12 - mu12;
                    f32x2 num = (2.f * mu12 + c1) * (2.f * sg12 + c2);
                    f32x2 den = (mu1s + mu2s + c1) * (sg1 + sg2 + c2);
                    float sx = num.x * __builtin_amdgcn_rcpf(den.x);
                    float sy = num.y * __builtin_amdgcn_rcpf(den.y);
                    if (orow0 < HO)     lsum += sx;
                    if (orow0 + 1 < HO) lsum += sy;
                }
            }
        }
    }

    // ---------- reduction ----------
    #pragma unroll
    for (int off = 32; off; off >>= 1)
        lsum += __shfl_down(lsum, off, 64);
    __syncthreads();                      // vbuf reads done -> reuse for partials
    if ((tid & 63) == 0) vbuf[tid >> 6] = lsum;
    __syncthreads();
    if (tid == 0) {
        double t = (double)vbuf[0] + (double)vbuf[1] +
                   (double)vbuf[2] + (double)vbuf[3];
        atomicAdd(acc, t);
    }
}

__global__ void ssim_finalize(const double* __restrict__ acc,
                              float* __restrict__ out)
{
    out[0] = (float)(acc[0] / (double)(16LL * 3LL * (long long)HO * (long long)WO));
}

extern "C" void kernel_launch(void* const* d_in, const int* in_sizes, int n_in,
                              void* d_out, int out_size, void* d_ws, size_t ws_size,
                              hipStream_t stream) {
    const float* img1 = (const float*)d_in[0];
    const float* img2 = (const float*)d_in[1];
    const float* win  = (const float*)d_in[2];  // (3,1,11,11); channels identical
    float* out = (float*)d_out;
    double* acc = (double*)d_ws;

    hipMemsetAsync(acc, 0, sizeof(double), stream);

    dim3 grid((WO + OTW - 1) / OTW, (HO + OTH - 1) / OTH, 16 * 3);
    ssim_sep_kernel<<<grid, 256, 0, stream>>>(img1, img2, win, acc);
    ssim_finalize<<<1, 1, 0, stream>>>(acc, out);
}

// Round 9
// 79.869 us; speedup vs baseline: 3.3594x; 1.4328x over previous
//
#include <hip/hip_runtime.h>

#define HH 512
#define WW 512
#define HO 502
#define WO 502
#define KS 11
#define OTH 32                 // v-rows per tile
#define RPT 8                  // v-rows per thread (4 groups of 64 lanes)
#define NR  (RPT + KS - 1)     // 18 input rows per thread
#define OTW 48                 // output cols per tile
#define VW  58                 // v-cols = OTW + KS - 1
#define RS  34                 // row stride (even -> aligned b64 pairs, conflict-free)
#define CHS (VW * RS)          // 1972 dwords per channel
#define CPT 4                  // output cols per thread in phase 2
#define NPOS (CPT + KS - 1)    // 14 tap positions
#define NCG 12                 // active col groups (12*4 = 48)
#define ZC  4                  // z-slices per block (software pipelined)

typedef float f32x2 __attribute__((ext_vector_type(2)));

// symmetric gaussian lookup, k compile-time
#define GW(k) g[(k) < 6 ? (k) : 10 - (k)]

__global__ __launch_bounds__(256)
void ssim_sep_kernel(
    const float* __restrict__ img1, const float* __restrict__ img2,
    const float* __restrict__ win, double* __restrict__ acc)
{
    __shared__ __align__(16) float vbuf[5 * CHS];   // 39,440 B -> 4 blocks/CU
    __shared__ float wsum[4];

    const int tid = threadIdx.x;
    const int tile_c0 = blockIdx.x * OTW;
    const int tile_r0 = blockIdx.y * OTH;

    // 1-D gaussian from separable 2-D window: g[k] = w[5][k]/sqrt(w[5][5]); symmetric
    float g[6];
    {
        double inv = 1.0 / sqrt((double)win[5 * KS + 5]);
        #pragma unroll
        for (int k = 0; k < 6; ++k)
            g[k] = (float)((double)win[5 * KS + k] * inv);
    }

    // ---- per-block constants for phase 1 ----
    const int lane = tid & 63;              // v column
    const int j0 = (tid >> 6) * RPT;        // first v-row owned (0,8,16,24)
    int gc = tile_c0 + lane;
    if (gc > WW - 1) gc = WW - 1;           // clamped cols feed only discarded outputs

    // per-thread precomputed row offsets (wave-uniform rows, clamped)
    const int r0 = tile_r0 + j0;

    const size_t zstride = (size_t)HH * WW;
    const float* p1 = img1 + (size_t)blockIdx.z * ZC * zstride;
    const float* p2 = img2 + (size_t)blockIdx.z * ZC * zstride;

    float a[NR], b[NR];
    // issue loads for t = 0
    #pragma unroll
    for (int ri = 0; ri < NR; ++ri) {
        int gr = r0 + ri;
        if (gr > HH - 1) gr = HH - 1;
        const size_t ro = (size_t)gr * WW + gc;
        a[ri] = p1[ro];
        b[ri] = p2[ro];
    }

    // phase-2 constants
    const int rp = tid & 15;                // row pair: rows 2rp, 2rp+1
    const int cg = tid >> 4;                // col group 0..15, active < 12
    const int c0 = cg * CPT;
    const int rb = 2 * rp;

    const float c1 = 1e-4f, c2 = 9e-4f;     // L = 1 for [0,1) inputs
    float lsum = 0.f;

    for (int t = 0; t < ZC; ++t) {
        // ---------- phase 1 compute: vertical conv (channel-paired pk math) ----------
        f32x2 m12[RPT], ee[RPT];
        float e12[RPT];
        #pragma unroll
        for (int j = 0; j < RPT; ++j) {
            m12[j] = (f32x2){0.f, 0.f};
            ee[j]  = (f32x2){0.f, 0.f};
            e12[j] = 0.f;
        }
        #pragma unroll
        for (int ri = 0; ri < NR; ++ri) {
            float av = a[ri], bv = b[ri];
            f32x2 xab = {av, bv};
            f32x2 xsq = xab * xab;          // pk_mul {aa, bb}
            float ab = av * bv;
            #pragma unroll
            for (int j = 0; j < RPT; ++j) {
                int k = ri - j;
                if (k >= 0 && k < KS) {     // folds at compile time
                    float w = GW(k);
                    m12[j] += w * xab;      // pk_fma
                    ee[j]  += w * xsq;      // pk_fma
                    e12[j] += w * ab;
                }
            }
        }

        __syncthreads();                    // prior phase-2 reads of vbuf complete

        if (lane < VW) {
            const int cb = lane * RS + j0;
            #pragma unroll
            for (int j = 0; j < RPT; ++j) {
                vbuf[0 * CHS + cb + j] = m12[j].x;
                vbuf[1 * CHS + cb + j] = m12[j].y;
                vbuf[2 * CHS + cb + j] = ee[j].x;
                vbuf[3 * CHS + cb + j] = ee[j].y;
                vbuf[4 * CHS + cb + j] = e12[j];
            }
        }

        // issue next z-slice's loads now; waitcnt lands after phase 2 (latency hidden)
        if (t + 1 < ZC) {
            p1 += zstride;
            p2 += zstride;
            #pragma unroll
            for (int ri = 0; ri < NR; ++ri) {
                int gr = r0 + ri;
                if (gr > HH - 1) gr = HH - 1;
                const size_t ro = (size_t)gr * WW + gc;
                a[ri] = p1[ro];
                b[ri] = p2[ro];
            }
        }

        __syncthreads();                    // vbuf writes visible

        // ---------- phase 2: horizontal conv + SSIM (row-paired pk, b64 reads) ----------
        if (cg < NCG) {
            f32x2 am[5][CPT];
            #pragma unroll
            for (int ch = 0; ch < 5; ++ch)
                #pragma unroll
                for (int j = 0; j < CPT; ++j) am[ch][j] = (f32x2){0.f, 0.f};

            #pragma unroll
            for (int ch = 0; ch < 5; ++ch) {
                const float* vp = &vbuf[ch * CHS + rb];
                #pragma unroll
                for (int i = 0; i < NPOS; ++i) {
                    // aligned 8B: (c0+i)*34 + 2rp is even
                    f32x2 v = *reinterpret_cast<const f32x2*>(&vp[(c0 + i) * RS]);
                    #pragma unroll
                    for (int j = 0; j < CPT; ++j) {
                        int k = i - j;
                        if (k >= 0 && k < KS)        // folds at compile time
                            am[ch][j] += GW(k) * v;  // pk_fma
                    }
                }
            }

            const int orow0 = tile_r0 + rb;
            #pragma unroll
            for (int j = 0; j < CPT; ++j) {
                int ocol = tile_c0 + c0 + j;
                if (ocol < WO) {
                    f32x2 mu1 = am[0][j], mu2 = am[1][j];
                    f32x2 e11 = am[2][j], e22 = am[3][j], e12v = am[4][j];
                    f32x2 mu1s = mu1 * mu1, mu2s = mu2 * mu2, mu12 = mu1 * mu2;
                    f32x2 sg1 = e11 - mu1s, sg2 = e22 - mu2s, sg12 = e12v - mu12;
                    f32x2 num = (2.f * mu12 + c1) * (2.f * sg12 + c2);
                    f32x2 den = (mu1s + mu2s + c1) * (sg1 + sg2 + c2);
                    float sx = num.x * __builtin_amdgcn_rcpf(den.x);
                    float sy = num.y * __builtin_amdgcn_rcpf(den.y);
                    if (orow0 < HO)     lsum += sx;
                    if (orow0 + 1 < HO) lsum += sy;
                }
            }
        }
    }

    // ---------- reduction ----------
    #pragma unroll
    for (int off = 32; off; off >>= 1)
        lsum += __shfl_down(lsum, off, 64);
    if ((tid & 63) == 0) wsum[tid >> 6] = lsum;
    __syncthreads();
    if (tid == 0) {
        double tt = (double)wsum[0] + (double)wsum[1] +
                    (double)wsum[2] + (double)wsum[3];
        atomicAdd(acc, tt);
    }
}

__global__ void ssim_finalize(const double* __restrict__ acc,
                              float* __restrict__ out)
{
    out[0] = (float)(acc[0] / (double)(16LL * 3LL * (long long)HO * (long long)WO));
}

extern "C" void kernel_launch(void* const* d_in, const int* in_sizes, int n_in,
                              void* d_out, int out_size, void* d_ws, size_t ws_size,
                              hipStream_t stream) {
    const float* img1 = (const float*)d_in[0];
    const float* img2 = (const float*)d_in[1];
    const float* win  = (const float*)d_in[2];  // (3,1,11,11); channels identical
    float* out = (float*)d_out;
    double* acc = (double*)d_ws;

    hipMemsetAsync(acc, 0, sizeof(double), stream);

    dim3 grid((WO + OTW - 1) / OTW,            // 11
              (HO + OTH - 1) / OTH,            // 16
              (16 * 3) / ZC);                  // 12
    ssim_sep_kernel<<<grid, 256, 0, stream>>>(img1, img2, win, acc);
    ssim_finalize<<<1, 1, 0, stream>>>(acc, out);
}

// Round 10
// 79.693 us; speedup vs baseline: 3.3668x; 1.0022x over previous
//
#include <hip/hip_runtime.h>

#define HH 512
#define WW 512
#define HO 502
#define WO 502
#define KS 11
#define OTH 32                 // v-rows per tile
#define RPT 8                  // v-rows per thread (4 groups of 64 lanes)
#define NR  (RPT + KS - 1)     // 18 input rows per thread
#define OTW 48                 // output cols per tile
#define VW  58                 // v-cols = OTW + KS - 1
#define RS  34                 // row stride (even -> aligned b64 pairs, conflict-free)
#define CHS (VW * RS)          // 1972 dwords per channel
#define CPT 4                  // output cols per thread in phase 2
#define NPOS (CPT + KS - 1)    // 14 tap positions
#define NCG 12                 // active col groups (12*4 = 48)

#define NTX 11                 // x tiles (11*48 = 528 >= 502)
#define NTY 16                 // y tiles (16*32 = 512 >= 502)
#define NTILES (NTX * NTY)     // 176
#define NZ 48                  // B*C planes
#define TOTW (NTILES * NZ)     // 8448 tile-slices
#define NBLK 1024              // exact resident capacity: 4 blocks/CU * 256 CU
#define WQ (TOTW / NBLK)       // 8
#define WR (TOTW % NBLK)       // 256 blocks take one extra

typedef float f32x2 __attribute__((ext_vector_type(2)));

// symmetric gaussian lookup, k compile-time
#define GW(k) g[(k) < 6 ? (k) : 10 - (k)]

__global__ __launch_bounds__(256)
void ssim_sep_kernel(
    const float* __restrict__ img1, const float* __restrict__ img2,
    const float* __restrict__ win, double* __restrict__ acc)
{
    __shared__ __align__(16) float vbuf[5 * CHS];   // 39,440 B -> 4 blocks/CU
    __shared__ float wsum[4];

    const int tid = threadIdx.x;
    const int bid = blockIdx.x;

    // 1-D gaussian from separable 2-D window: g[k] = w[5][k]/sqrt(w[5][5]); symmetric
    float g[6];
    {
        double inv = 1.0 / sqrt((double)win[5 * KS + 5]);
        #pragma unroll
        for (int k = 0; k < 6; ++k)
            g[k] = (float)((double)win[5 * KS + k] * inv);
    }

    // ---- fixed per-thread roles ----
    const int lane = tid & 63;              // v column
    const int j0 = (tid >> 6) * RPT;        // first v-row owned (0,8,16,24)
    const int rp = tid & 15;                // phase-2 row pair
    const int cg = tid >> 4;                // phase-2 col group, active < NCG
    const int c0 = cg * CPT;
    const int rb = 2 * rp;
    const size_t zstride = (size_t)HH * WW;
    const float c1 = 1e-4f, c2 = 9e-4f;     // L = 1 for [0,1) inputs

    // ---- work chunk: contiguous [w0, w0+cnt) of 8448 tile-slices ----
    int w0, cnt;
    if (bid < WR) { w0 = bid * (WQ + 1);            cnt = WQ + 1; }
    else          { w0 = WR * (WQ + 1) + (bid - WR) * WQ; cnt = WQ; }

    // issue global loads for work item w into a[]/b[] (macro: same regs each time)
    float a[NR], b[NR];
#define ISSUE_LOADS(wv)                                                \
    {                                                                  \
        int z_   = (wv) / NTILES;                                      \
        int rem_ = (wv) % NTILES;                                      \
        int ty_  = rem_ / NTX;                                         \
        int tx_  = rem_ % NTX;                                         \
        const float* p1_ = img1 + (size_t)z_ * zstride;                \
        const float* p2_ = img2 + (size_t)z_ * zstride;                \
        int gc_ = tx_ * OTW + lane;                                    \
        if (gc_ > WW - 1) gc_ = WW - 1;                                \
        int r0_ = ty_ * OTH + j0;                                      \
        _Pragma("unroll")                                              \
        for (int ri = 0; ri < NR; ++ri) {                              \
            int gr = r0_ + ri;                                         \
            if (gr > HH - 1) gr = HH - 1;                              \
            size_t ro = (size_t)gr * WW + gc_;                         \
            a[ri] = p1_[ro];                                           \
            b[ri] = p2_[ro];                                           \
        }                                                              \
    }

    int w = w0;
    int ctx = (w % NTILES) % NTX;           // current tile coords (for output masks)
    int cty = (w % NTILES) / NTX;
    ISSUE_LOADS(w);

    float lsum = 0.f;

    for (int i = 0; i < cnt; ++i) {
        // ---------- phase 1 compute: vertical conv (channel-paired pk math) ----------
        f32x2 m12[RPT], ee[RPT];
        float e12[RPT];
        #pragma unroll
        for (int j = 0; j < RPT; ++j) {
            m12[j] = (f32x2){0.f, 0.f};
            ee[j]  = (f32x2){0.f, 0.f};
            e12[j] = 0.f;
        }
        #pragma unroll
        for (int ri = 0; ri < NR; ++ri) {
            float av = a[ri], bv = b[ri];
            f32x2 xab = {av, bv};
            f32x2 xsq = xab * xab;          // pk_mul {aa, bb}
            float ab = av * bv;
            #pragma unroll
            for (int j = 0; j < RPT; ++j) {
                int k = ri - j;
                if (k >= 0 && k < KS) {     // folds at compile time
                    float wk = GW(k);
                    m12[j] += wk * xab;     // pk_fma
                    ee[j]  += wk * xsq;     // pk_fma
                    e12[j] += wk * ab;
                }
            }
        }

        __syncthreads();                    // prior phase-2 reads of vbuf complete

        if (lane < VW) {
            const int cb = lane * RS + j0;
            #pragma unroll
            for (int j = 0; j < RPT; ++j) {
                vbuf[0 * CHS + cb + j] = m12[j].x;
                vbuf[1 * CHS + cb + j] = m12[j].y;
                vbuf[2 * CHS + cb + j] = ee[j].x;
                vbuf[3 * CHS + cb + j] = ee[j].y;
                vbuf[4 * CHS + cb + j] = e12[j];
            }
        }

        // issue next work item's loads now; waitcnt lands after phase 2
        int ntx = ctx, nty = cty;
        if (i + 1 < cnt) {
            int wn = w + 1;
            ntx = (wn % NTILES) % NTX;
            nty = (wn % NTILES) / NTX;
            ISSUE_LOADS(wn);
            w = wn;
        }

        __syncthreads();                    // vbuf writes visible

        // ---------- phase 2: horizontal conv + SSIM (row-paired pk, b64 reads) ----------
        if (cg < NCG) {
            f32x2 am[5][CPT];
            #pragma unroll
            for (int ch = 0; ch < 5; ++ch)
                #pragma unroll
                for (int j = 0; j < CPT; ++j) am[ch][j] = (f32x2){0.f, 0.f};

            #pragma unroll
            for (int ch = 0; ch < 5; ++ch) {
                const float* vp = &vbuf[ch * CHS + rb];
                #pragma unroll
                for (int t = 0; t < NPOS; ++t) {
                    // aligned 8B: (c0+t)*34 + 2rp is even
                    f32x2 v = *reinterpret_cast<const f32x2*>(&vp[(c0 + t) * RS]);
                    #pragma unroll
                    for (int j = 0; j < CPT; ++j) {
                        int k = t - j;
                        if (k >= 0 && k < KS)        // folds at compile time
                            am[ch][j] += GW(k) * v;  // pk_fma
                    }
                }
            }

            const int orow0 = cty * OTH + rb;
            #pragma unroll
            for (int j = 0; j < CPT; ++j) {
                int ocol = ctx * OTW + c0 + j;
                if (ocol < WO) {
                    f32x2 mu1 = am[0][j], mu2 = am[1][j];
                    f32x2 e11 = am[2][j], e22 = am[3][j], e12v = am[4][j];
                    f32x2 mu1s = mu1 * mu1, mu2s = mu2 * mu2, mu12 = mu1 * mu2;
                    f32x2 sg1 = e11 - mu1s, sg2 = e22 - mu2s, sg12 = e12v - mu12;
                    f32x2 num = (2.f * mu12 + c1) * (2.f * sg12 + c2);
                    f32x2 den = (mu1s + mu2s + c1) * (sg1 + sg2 + c2);
                    float sx = num.x * __builtin_amdgcn_rcpf(den.x);
                    float sy = num.y * __builtin_amdgcn_rcpf(den.y);
                    if (orow0 < HO)     lsum += sx;
                    if (orow0 + 1 < HO) lsum += sy;
                }
            }
        }

        ctx = ntx; cty = nty;
    }

    // ---------- reduction ----------
    #pragma unroll
    for (int off = 32; off; off >>= 1)
        lsum += __shfl_down(lsum, off, 64);
    if ((tid & 63) == 0) wsum[tid >> 6] = lsum;
    __syncthreads();
    if (tid == 0) {
        double tt = (double)wsum[0] + (double)wsum[1] +
                    (double)wsum[2] + (double)wsum[3];
        atomicAdd(acc, tt);
    }
}

__global__ void ssim_finalize(const double* __restrict__ acc,
                              float* __restrict__ out)
{
    out[0] = (float)(acc[0] / (double)(16LL * 3LL * (long long)HO * (long long)WO));
}

extern "C" void kernel_launch(void* const* d_in, const int* in_sizes, int n_in,
                              void* d_out, int out_size, void* d_ws, size_t ws_size,
                              hipStream_t stream) {
    const float* img1 = (const float*)d_in[0];
    const float* img2 = (const float*)d_in[1];
    const float* win  = (const float*)d_in[2];  // (3,1,11,11); channels identical
    float* out = (float*)d_out;
    double* acc = (double*)d_ws;

    hipMemsetAsync(acc, 0, sizeof(double), stream);

    ssim_sep_kernel<<<dim3(NBLK), 256, 0, stream>>>(img1, img2, win, acc);
    ssim_finalize<<<1, 1, 0, stream>>>(acc, out);
}

// Round 11
// 73.469 us; speedup vs baseline: 3.6520x; 1.0847x over previous
//
#include <hip/hip_runtime.h>

#define HH 512
#define WW 512
#define HO 502
#define WO 502
#define KS 11
#define OTH 32                 // v-rows per tile
#define RPT 8                  // v-rows per thread (4 groups of 64 lanes)
#define NR  (RPT + KS - 1)     // 18 input rows per thread
#define OTW 48                 // output cols per tile
#define VW  58                 // v-cols = OTW + KS - 1
#define RS  34                 // row stride (even -> aligned b64 pairs, conflict-free)
#define CHS (VW * RS)          // 1972 dwords per channel
#define CPT 4                  // output cols per thread in phase 2
#define NPOS (CPT + KS - 1)    // 14 tap positions
#define NCG 12                 // active col groups (12*4 = 48)

#define NTX 11                 // x tiles (11*48 = 528 >= 502)
#define NTY 16                 // y tiles (16*32 = 512 >= 502)
#define NTILES (NTX * NTY)     // 176
#define NZ 48                  // B*C planes
#define TOTW (NTILES * NZ)     // 8448 tile-slices
#define NBLK 1024              // resident capacity at 4 blocks/CU
#define WQ (TOTW / NBLK)       // 8
#define WR (TOTW % NBLK)       // 256 blocks take one extra

typedef float f32x2 __attribute__((ext_vector_type(2)));

// symmetric gaussian lookup, k compile-time
#define GW(k) g[(k) < 6 ? (k) : 10 - (k)]

__global__ __launch_bounds__(256)
void ssim_sep_kernel(
    const float* __restrict__ img1, const float* __restrict__ img2,
    const float* __restrict__ win, double* __restrict__ acc)
{
    // 4 channels: {mu_s, mu_d, E[s^2], E[d^2]} with s=x+y, d=x-y
    __shared__ __align__(16) float vbuf[4 * CHS];   // 31,552 B
    __shared__ float wsum[4];

    const int tid = threadIdx.x;
    const int bid = blockIdx.x;

    // 1-D gaussian from separable 2-D window: g[k] = w[5][k]/sqrt(w[5][5]); symmetric
    float g[6];
    {
        double inv = 1.0 / sqrt((double)win[5 * KS + 5]);
        #pragma unroll
        for (int k = 0; k < 6; ++k)
            g[k] = (float)((double)win[5 * KS + k] * inv);
    }

    // ---- fixed per-thread roles ----
    const int lane = tid & 63;              // v column
    const int j0 = (tid >> 6) * RPT;        // first v-row owned (0,8,16,24)
    const int rp = tid & 15;                // phase-2 row pair
    const int cg = tid >> 4;                // phase-2 col group, active < NCG
    const int c0 = cg * CPT;
    const int rb = 2 * rp;
    const size_t zstride = (size_t)HH * WW;
    const float c1 = 1e-4f, c2 = 9e-4f;     // L = 1 for [0,1) inputs

    // ---- work chunk: contiguous [w0, w0+cnt) of 8448 tile-slices ----
    int w0, cnt;
    if (bid < WR) { w0 = bid * (WQ + 1);            cnt = WQ + 1; }
    else          { w0 = WR * (WQ + 1) + (bid - WR) * WQ; cnt = WQ; }

    // issue global loads for work item w; immediately fold into s=a+b, d=a-b
    float sv[NR], dv[NR];
#define ISSUE_LOADS(wv)                                                \
    {                                                                  \
        int z_   = (wv) / NTILES;                                      \
        int rem_ = (wv) % NTILES;                                      \
        int ty_  = rem_ / NTX;                                         \
        int tx_  = rem_ % NTX;                                         \
        const float* p1_ = img1 + (size_t)z_ * zstride;                \
        const float* p2_ = img2 + (size_t)z_ * zstride;                \
        int gc_ = tx_ * OTW + lane;                                    \
        if (gc_ > WW - 1) gc_ = WW - 1;                                \
        int r0_ = ty_ * OTH + j0;                                      \
        _Pragma("unroll")                                              \
        for (int ri = 0; ri < NR; ++ri) {                              \
            int gr = r0_ + ri;                                         \
            if (gr > HH - 1) gr = HH - 1;                              \
            size_t ro = (size_t)gr * WW + gc_;                         \
            float a_ = p1_[ro];                                        \
            float b_ = p2_[ro];                                        \
            sv[ri] = a_ + b_;                                          \
            dv[ri] = a_ - b_;                                          \
        }                                                              \
    }

    int w = w0;
    int ctx = (w % NTILES) % NTX;           // current tile coords (for output masks)
    int cty = (w % NTILES) / NTX;
    ISSUE_LOADS(w);

    float lsum = 0.f;

    for (int i = 0; i < cnt; ++i) {
        // ---------- phase 1: vertical conv, 4 channels, fully packed ----------
        f32x2 mu[RPT], es[RPT];             // {mu_s,mu_d}, {E[s2],E[d2]}
        #pragma unroll
        for (int j = 0; j < RPT; ++j) {
            mu[j] = (f32x2){0.f, 0.f};
            es[j] = (f32x2){0.f, 0.f};
        }
        #pragma unroll
        for (int ri = 0; ri < NR; ++ri) {
            f32x2 sd = {sv[ri], dv[ri]};
            f32x2 sq = sd * sd;             // pk_mul {s2, d2}
            #pragma unroll
            for (int j = 0; j < RPT; ++j) {
                int k = ri - j;
                if (k >= 0 && k < KS) {     // folds at compile time
                    float wk = GW(k);
                    mu[j] += wk * sd;       // pk_fma
                    es[j] += wk * sq;       // pk_fma
                }
            }
        }

        __syncthreads();                    // prior phase-2 reads of vbuf complete

        if (lane < VW) {
            const int cb = lane * RS + j0;
            #pragma unroll
            for (int j = 0; j < RPT; ++j) {
                vbuf[0 * CHS + cb + j] = mu[j].x;
                vbuf[1 * CHS + cb + j] = mu[j].y;
                vbuf[2 * CHS + cb + j] = es[j].x;
                vbuf[3 * CHS + cb + j] = es[j].y;
            }
        }

        // issue next work item's loads now; waitcnt lands after phase 2
        int ntx = ctx, nty = cty;
        if (i + 1 < cnt) {
            int wn = w + 1;
            ntx = (wn % NTILES) % NTX;
            nty = (wn % NTILES) / NTX;
            ISSUE_LOADS(wn);
            w = wn;
        }

        __syncthreads();                    // vbuf writes visible

        // ---------- phase 2: horizontal conv + SSIM (row-paired pk, b64 reads) ----------
        if (cg < NCG) {
            f32x2 am[4][CPT];
            #pragma unroll
            for (int ch = 0; ch < 4; ++ch)
                #pragma unroll
                for (int j = 0; j < CPT; ++j) am[ch][j] = (f32x2){0.f, 0.f};

            #pragma unroll
            for (int ch = 0; ch < 4; ++ch) {
                const float* vp = &vbuf[ch * CHS + rb];
                #pragma unroll
                for (int t = 0; t < NPOS; ++t) {
                    // aligned 8B: (c0+t)*34 + 2rp is even
                    f32x2 v = *reinterpret_cast<const f32x2*>(&vp[(c0 + t) * RS]);
                    #pragma unroll
                    for (int j = 0; j < CPT; ++j) {
                        int k = t - j;
                        if (k >= 0 && k < KS)        // folds at compile time
                            am[ch][j] += GW(k) * v;  // pk_fma
                    }
                }
            }

            const int orow0 = cty * OTH + rb;
            #pragma unroll
            for (int j = 0; j < CPT; ++j) {
                int ocol = ctx * OTW + c0 + j;
                if (ocol < WO) {
                    f32x2 mus = am[0][j], mud = am[1][j];
                    f32x2 Es  = am[2][j], Ed  = am[3][j];
                    f32x2 ps = mus * mus, pd = mud * mud;
                    f32x2 A  = 0.5f * (ps - pd);           // 2*mu1*mu2
                    f32x2 Bm = 0.5f * (ps + pd);           // mu1^2 + mu2^2
                    f32x2 S12 = 0.5f * (Es - Ed) - A;      // 2*sigma12
                    f32x2 SS  = 0.5f * (Es + Ed) - Bm;     // sigma1^2 + sigma2^2
                    f32x2 num = (A + c1) * (S12 + c2);
                    f32x2 den = (Bm + c1) * (SS + c2);
                    float sx = num.x * __builtin_amdgcn_rcpf(den.x);
                    float sy = num.y * __builtin_amdgcn_rcpf(den.y);
                    if (orow0 < HO)     lsum += sx;
                    if (orow0 + 1 < HO) lsum += sy;
                }
            }
        }

        ctx = ntx; cty = nty;
    }

    // ---------- reduction ----------
    #pragma unroll
    for (int off = 32; off; off >>= 1)
        lsum += __shfl_down(lsum, off, 64);
    if ((tid & 63) == 0) wsum[tid >> 6] = lsum;
    __syncthreads();
    if (tid == 0) {
        double tt = (double)wsum[0] + (double)wsum[1] +
                    (double)wsum[2] + (double)wsum[3];
        atomicAdd(acc, tt);
    }
}

__global__ void ssim_finalize(const double* __restrict__ acc,
                              float* __restrict__ out)
{
    out[0] = (float)(acc[0] / (double)(16LL * 3LL * (long long)HO * (long long)WO));
}

extern "C" void kernel_launch(void* const* d_in, const int* in_sizes, int n_in,
                              void* d_out, int out_size, void* d_ws, size_t ws_size,
                              hipStream_t stream) {
    const float* img1 = (const float*)d_in[0];
    const float* img2 = (const float*)d_in[1];
    const float* win  = (const float*)d_in[2];  // (3,1,11,11); channels identical
    float* out = (float*)d_out;
    double* acc = (double*)d_ws;

    hipMemsetAsync(acc, 0, sizeof(double), stream);

    ssim_sep_kernel<<<dim3(NBLK), 256, 0, stream>>>(img1, img2, win, acc);
    ssim_finalize<<<1, 1, 0, stream>>>(acc, out);
}

// Round 12
// 70.640 us; speedup vs baseline: 3.7983x; 1.0400x over previous
//
#include <hip/hip_runtime.h>

#define HH 512
#define WW 512
#define HO 502
#define WO 502
#define KS 11
#define OTH 32                 // v-rows per tile
#define RPT 8                  // v-rows per thread (4 groups of 64 lanes)
#define NR  (RPT + KS - 1)     // 18 input rows per thread
#define OTW 48                 // output cols per tile
#define VW  58                 // v-cols = OTW + KS - 1
#define RS  34                 // row stride (even -> aligned b64 pairs)
#define CHS (VW * RS)          // 1972 dwords per channel
#define CPT 3                  // output cols per thread in phase 2 (16 groups x 3 = 48)
#define NPOS (CPT + KS - 1)    // 13 tap positions
#define NCG 16                 // all col groups active -> no idle wave in phase 2

#define NTX 11                 // x tiles (11*48 = 528 >= 502)
#define NTY 16                 // y tiles (16*32 = 512 >= 502)
#define NTILES (NTX * NTY)     // 176
#define NZ 48                  // B*C planes
#define TOTW (NTILES * NZ)     // 8448 tile-slices
#define NBLK 1024              // resident capacity at 4 blocks/CU
#define WQ (TOTW / NBLK)       // 8
#define WR (TOTW % NBLK)       // 256 blocks take one extra

typedef float f32x2 __attribute__((ext_vector_type(2)));

// symmetric gaussian lookup, k compile-time
#define GW(k) g[(k) < 6 ? (k) : 10 - (k)]

__global__ __launch_bounds__(256)
void ssim_sep_kernel(
    const float* __restrict__ img1, const float* __restrict__ img2,
    const float* __restrict__ win, double* __restrict__ acc)
{
    // 4 channels: {mu_s, mu_d, E[s^2], E[d^2]} with s=x+y, d=x-y
    __shared__ __align__(16) float vbuf[4 * CHS];   // 31,552 B
    __shared__ float wsum[4];

    const int tid = threadIdx.x;
    const int bid = blockIdx.x;

    // 1-D gaussian from separable 2-D window: g[k] = w[5][k]/sqrt(w[5][5]); symmetric
    float g[6];
    {
        double inv = 1.0 / sqrt((double)win[5 * KS + 5]);
        #pragma unroll
        for (int k = 0; k < 6; ++k)
            g[k] = (float)((double)win[5 * KS + k] * inv);
    }

    // ---- fixed per-thread roles ----
    const int lane = tid & 63;              // v column (phase 1)
    const int j0 = (tid >> 6) * RPT;        // first v-row owned (0,8,16,24)
    const int rp = tid & 15;                // phase-2 row pair
    const int cg = tid >> 4;                // phase-2 col group 0..15 (all active)
    const int c0 = cg * CPT;                // 0,3,...,45 ; max tap col 45+12=57=VW-1
    const int rb = 2 * rp;
    const size_t zstride = (size_t)HH * WW;
    const float c1 = 1e-4f, c2 = 9e-4f;     // L = 1 for [0,1) inputs

    // ---- work chunk: contiguous [w0, w0+cnt) of 8448 tile-slices ----
    int w0, cnt;
    if (bid < WR) { w0 = bid * (WQ + 1);            cnt = WQ + 1; }
    else          { w0 = WR * (WQ + 1) + (bid - WR) * WQ; cnt = WQ; }

    // issue global loads for work item w; immediately fold into s=a+b, d=a-b
    float sv[NR], dv[NR];
#define ISSUE_LOADS(wv)                                                \
    {                                                                  \
        int z_   = (wv) / NTILES;                                      \
        int rem_ = (wv) % NTILES;                                      \
        int ty_  = rem_ / NTX;                                         \
        int tx_  = rem_ % NTX;                                         \
        const float* p1_ = img1 + (size_t)z_ * zstride;                \
        const float* p2_ = img2 + (size_t)z_ * zstride;                \
        int gc_ = tx_ * OTW + lane;                                    \
        if (gc_ > WW - 1) gc_ = WW - 1;                                \
        int r0_ = ty_ * OTH + j0;                                      \
        _Pragma("unroll")                                              \
        for (int ri = 0; ri < NR; ++ri) {                              \
            int gr = r0_ + ri;                                         \
            if (gr > HH - 1) gr = HH - 1;                              \
            size_t ro = (size_t)gr * WW + gc_;                         \
            float a_ = p1_[ro];                                        \
            float b_ = p2_[ro];                                        \
            sv[ri] = a_ + b_;                                          \
            dv[ri] = a_ - b_;                                          \
        }                                                              \
    }

    int w = w0;
    int ctx = (w % NTILES) % NTX;           // current tile coords (for output masks)
    int cty = (w % NTILES) / NTX;
    ISSUE_LOADS(w);

    float lsum = 0.f;

    for (int i = 0; i < cnt; ++i) {
        // ---------- phase 1: vertical conv, 4 channels, fully packed ----------
        f32x2 mu[RPT], es[RPT];             // {mu_s,mu_d}, {E[s2],E[d2]}
        #pragma unroll
        for (int j = 0; j < RPT; ++j) {
            mu[j] = (f32x2){0.f, 0.f};
            es[j] = (f32x2){0.f, 0.f};
        }
        #pragma unroll
        for (int ri = 0; ri < NR; ++ri) {
            f32x2 sd = {sv[ri], dv[ri]};
            f32x2 sq = sd * sd;             // pk_mul {s2, d2}
            #pragma unroll
            for (int j = 0; j < RPT; ++j) {
                int k = ri - j;
                if (k >= 0 && k < KS) {     // folds at compile time
                    float wk = GW(k);
                    mu[j] += wk * sd;       // pk_fma
                    es[j] += wk * sq;       // pk_fma
                }
            }
        }

        __syncthreads();                    // prior phase-2 reads of vbuf complete

        if (lane < VW) {
            const int cb = lane * RS + j0;
            #pragma unroll
            for (int j = 0; j < RPT; ++j) {
                vbuf[0 * CHS + cb + j] = mu[j].x;
                vbuf[1 * CHS + cb + j] = mu[j].y;
                vbuf[2 * CHS + cb + j] = es[j].x;
                vbuf[3 * CHS + cb + j] = es[j].y;
            }
        }

        // issue next work item's loads now; waitcnt lands after phase 2
        int ntx = ctx, nty = cty;
        if (i + 1 < cnt) {
            int wn = w + 1;
            ntx = (wn % NTILES) % NTX;
            nty = (wn % NTILES) / NTX;
            ISSUE_LOADS(wn);
            w = wn;
        }

        __syncthreads();                    // vbuf writes visible

        // ---------- phase 2: horizontal conv + SSIM (all 4 waves active) ----------
        {
            f32x2 am[4][CPT];
            #pragma unroll
            for (int ch = 0; ch < 4; ++ch)
                #pragma unroll
                for (int j = 0; j < CPT; ++j) am[ch][j] = (f32x2){0.f, 0.f};

            #pragma unroll
            for (int ch = 0; ch < 4; ++ch) {
                const float* vp = &vbuf[ch * CHS + rb];
                #pragma unroll
                for (int t = 0; t < NPOS; ++t) {
                    // aligned 8B: (c0+t)*34 + 2rp is even
                    f32x2 v = *reinterpret_cast<const f32x2*>(&vp[(c0 + t) * RS]);
                    #pragma unroll
                    for (int j = 0; j < CPT; ++j) {
                        int k = t - j;
                        if (k >= 0 && k < KS)        // folds at compile time
                            am[ch][j] += GW(k) * v;  // pk_fma
                    }
                }
            }

            const int orow0 = cty * OTH + rb;
            #pragma unroll
            for (int j = 0; j < CPT; ++j) {
                int ocol = ctx * OTW + c0 + j;
                if (ocol < WO) {
                    f32x2 mus = am[0][j], mud = am[1][j];
                    f32x2 Es  = am[2][j], Ed  = am[3][j];
                    f32x2 ps = mus * mus, pd = mud * mud;
                    f32x2 A  = 0.5f * (ps - pd);           // 2*mu1*mu2
                    f32x2 Bm = 0.5f * (ps + pd);           // mu1^2 + mu2^2
                    f32x2 S12 = 0.5f * (Es - Ed) - A;      // 2*sigma12
                    f32x2 SS  = 0.5f * (Es + Ed) - Bm;     // sigma1^2 + sigma2^2
                    f32x2 num = (A + c1) * (S12 + c2);
                    f32x2 den = (Bm + c1) * (SS + c2);
                    float sx = num.x * __builtin_amdgcn_rcpf(den.x);
                    float sy = num.y * __builtin_amdgcn_rcpf(den.y);
                    if (orow0 < HO)     lsum += sx;
                    if (orow0 + 1 < HO) lsum += sy;
                }
            }
        }

        ctx = ntx; cty = nty;
    }

    // ---------- reduction ----------
    #pragma unroll
    for (int off = 32; off; off >>= 1)
        lsum += __shfl_down(lsum, off, 64);
    if ((tid & 63) == 0) wsum[tid >> 6] = lsum;
    __syncthreads();
    if (tid == 0) {
        double tt = (double)wsum[0] + (double)wsum[1] +
                    (double)wsum[2] + (double)wsum[3];
        atomicAdd(acc, tt);
    }
}

__global__ void ssim_finalize(const double* __restrict__ acc,
                              float* __restrict__ out)
{
    out[0] = (float)(acc[0] / (double)(16LL * 3LL * (long long)HO * (long long)WO));
}

extern "C" void kernel_launch(void* const* d_in, const int* in_sizes, int n_in,
                              void* d_out, int out_size, void* d_ws, size_t ws_size,
                              hipStream_t stream) {
    const float* img1 = (const float*)d_in[0];
    const float* img2 = (const float*)d_in[1];
    const float* win  = (const float*)d_in[2];  // (3,1,11,11); channels identical
    float* out = (float*)d_out;
    double* acc = (double*)d_ws;

    hipMemsetAsync(acc, 0, sizeof(double), stream);

    ssim_sep_kernel<<<dim3(NBLK), 256, 0, stream>>>(img1, img2, win, acc);
    ssim_finalize<<<1, 1, 0, stream>>>(acc, out);
}

// Round 13
// 63.382 us; speedup vs baseline: 4.2333x; 1.1145x over previous
//
#include <hip/hip_runtime.h>

#define HH 512
#define WW 512
#define HO 502
#define WO 502
#define KS 11
#define OTH 32                 // v-rows per tile
#define RPT 8                  // v-rows per wave (4 waves)
#define NR  (RPT + KS - 1)     // 18 input rows per thread
#define OTW 48                 // output cols per tile
#define VW  58                 // v-cols = OTW + KS - 1
#define RS  34                 // row stride (even -> aligned b64 pairs)
#define CHS (VW * RS)          // 1972 dwords per channel
#define CPT 3                  // output cols per thread in phase 2 (16 groups x 3)
#define NPOS (CPT + KS - 1)    // 13 tap positions

#define NTX 11                 // x tiles (11*48 = 528 >= 502)
#define NTY 16                 // y tiles (16*32 = 512 >= 502)
#define NTILES (NTX * NTY)     // 176
#define NZ 48                  // B*C planes
#define TOTW (NTILES * NZ)     // 8448 tile-slices
#define NBLK 1024              // resident capacity at 4 blocks/CU
#define WQ (TOTW / NBLK)       // 8
#define WR (TOTW % NBLK)       // 256 blocks take one extra

typedef float f32x2 __attribute__((ext_vector_type(2)));

// symmetric gaussian lookup, k compile-time
#define GW(k) g[(k) < 6 ? (k) : 10 - (k)]

__global__ __launch_bounds__(256)
void ssim_sep_kernel(
    const float* __restrict__ img1, const float* __restrict__ img2,
    const float* __restrict__ win, double* __restrict__ acc)
{
    // 4 channels: {mu_s, mu_d, E[s^2], E[d^2]} with s=x+y, d=x-y
    // Wave w exclusively owns v-rows [8w, 8w+8) -> NO cross-wave deps, NO barriers.
    __shared__ __align__(16) float vbuf[4 * CHS];   // 31,552 B
    __shared__ float wsum[4];

    const int tid = threadIdx.x;
    const int bid = blockIdx.x;

    // 1-D gaussian from separable 2-D window: g[k] = w[5][k]/sqrt(w[5][5]); symmetric
    float g[6];
    {
        double inv = 1.0 / sqrt((double)win[5 * KS + 5]);
        #pragma unroll
        for (int k = 0; k < 6; ++k)
            g[k] = (float)((double)win[5 * KS + k] * inv);
    }

    // ---- fixed per-thread roles ----
    const int lane = tid & 63;              // phase-1 v column
    const int wv   = tid >> 6;              // wave id 0..3
    const int j0   = wv * RPT;              // first v-row owned by this wave
    // phase-2 roles are WITHIN-WAVE: rows come only from this wave's own group
    const int rp = lane & 3;                // row-pair within group (0..3)
    const int cg = lane >> 2;               // col group 0..15
    const int c0 = cg * CPT;                // 0,3,...,45 ; max tap col 45+12=57=VW-1
    const int rb = j0 + 2 * rp;             // v-row of .x lane; .y = rb+1
    const size_t zstride = (size_t)HH * WW;
    const float c1 = 1e-4f, c2 = 9e-4f;     // L = 1 for [0,1) inputs

    // ---- work chunk: contiguous [w0, w0+cnt) of 8448 tile-slices ----
    int w0, cnt;
    if (bid < WR) { w0 = bid * (WQ + 1);            cnt = WQ + 1; }
    else          { w0 = WR * (WQ + 1) + (bid - WR) * WQ; cnt = WQ; }

    // issue global loads for work item w into a[]/b[]; fold is DEFERRED to the
    // next iteration's phase 1 so the vmcnt wait lands after phase 2 (hidden).
    float a[NR], b[NR];
#define ISSUE_LOADS(wvv)                                               \
    {                                                                  \
        int z_   = (wvv) / NTILES;                                     \
        int rem_ = (wvv) % NTILES;                                     \
        int ty_  = rem_ / NTX;                                         \
        int tx_  = rem_ % NTX;                                         \
        const float* p1_ = img1 + (size_t)z_ * zstride;                \
        const float* p2_ = img2 + (size_t)z_ * zstride;                \
        int gc_ = tx_ * OTW + lane;                                    \
        if (gc_ > WW - 1) gc_ = WW - 1;                                \
        int r0_ = ty_ * OTH + j0;                                      \
        _Pragma("unroll")                                              \
        for (int ri = 0; ri < NR; ++ri) {                              \
            int gr = r0_ + ri;                                         \
            if (gr > HH - 1) gr = HH - 1;                              \
            size_t ro = (size_t)gr * WW + gc_;                         \
            a[ri] = p1_[ro];                                           \
            b[ri] = p2_[ro];                                           \
        }                                                              \
    }

    int w = w0;
    int ctx = (w % NTILES) % NTX;           // current tile coords (for output masks)
    int cty = (w % NTILES) / NTX;
    ISSUE_LOADS(w);

    float lsum = 0.f;

    for (int i = 0; i < cnt; ++i) {
        // ---------- fold s=a+b, d=a-b (vmcnt wait: loads issued ~1 item ago) ----------
        float sv[NR], dv[NR];
        #pragma unroll
        for (int ri = 0; ri < NR; ++ri) {
            sv[ri] = a[ri] + b[ri];
            dv[ri] = a[ri] - b[ri];
        }

        // ---------- phase 1: vertical conv, 4 channels, fully packed ----------
        f32x2 mu[RPT], es[RPT];             // {mu_s,mu_d}, {E[s2],E[d2]}
        #pragma unroll
        for (int j = 0; j < RPT; ++j) {
            mu[j] = (f32x2){0.f, 0.f};
            es[j] = (f32x2){0.f, 0.f};
        }
        #pragma unroll
        for (int ri = 0; ri < NR; ++ri) {
            f32x2 sd = {sv[ri], dv[ri]};
            f32x2 sq = sd * sd;             // pk_mul {s2, d2}
            #pragma unroll
            for (int j = 0; j < RPT; ++j) {
                int k = ri - j;
                if (k >= 0 && k < KS) {     // folds at compile time
                    float wk = GW(k);
                    mu[j] += wk * sd;       // pk_fma
                    es[j] += wk * sq;       // pk_fma
                }
            }
        }

        // own rows only -> no barrier needed anywhere
        if (lane < VW) {
            const int cb = lane * RS + j0;
            #pragma unroll
            for (int j = 0; j < RPT; ++j) {
                vbuf[0 * CHS + cb + j] = mu[j].x;
                vbuf[1 * CHS + cb + j] = mu[j].y;
                vbuf[2 * CHS + cb + j] = es[j].x;
                vbuf[3 * CHS + cb + j] = es[j].y;
            }
        }

        // issue next work item's loads now; consumed only at next fold (after phase 2)
        int ntx = ctx, nty = cty;
        if (i + 1 < cnt) {
            int wn = w + 1;
            ntx = (wn % NTILES) % NTX;
            nty = (wn % NTILES) / NTX;
            ISSUE_LOADS(wn);
            w = wn;
        }

        // own ds_writes retired before own ds_reads; memory clobber also pins
        // the global-load issue above and blocks ds_read hoisting.
        asm volatile("s_waitcnt lgkmcnt(0)" ::: "memory");

        // ---------- phase 2: horizontal conv + SSIM on OWN rows ----------
        {
            f32x2 am[4][CPT];
            #pragma unroll
            for (int ch = 0; ch < 4; ++ch)
                #pragma unroll
                for (int j = 0; j < CPT; ++j) am[ch][j] = (f32x2){0.f, 0.f};

            #pragma unroll
            for (int ch = 0; ch < 4; ++ch) {
                const float* vp = &vbuf[ch * CHS + rb];
                #pragma unroll
                for (int t = 0; t < NPOS; ++t) {
                    // aligned 8B: (c0+t)*34 + rb is even
                    f32x2 v = *reinterpret_cast<const f32x2*>(&vp[(c0 + t) * RS]);
                    #pragma unroll
                    for (int j = 0; j < CPT; ++j) {
                        int k = t - j;
                        if (k >= 0 && k < KS)        // folds at compile time
                            am[ch][j] += GW(k) * v;  // pk_fma
                    }
                }
            }

            const int orow0 = cty * OTH + rb;
            #pragma unroll
            for (int j = 0; j < CPT; ++j) {
                int ocol = ctx * OTW + c0 + j;
                if (ocol < WO) {
                    f32x2 mus = am[0][j], mud = am[1][j];
                    f32x2 Es  = am[2][j], Ed  = am[3][j];
                    f32x2 ps = mus * mus, pd = mud * mud;
                    f32x2 A  = 0.5f * (ps - pd);           // 2*mu1*mu2
                    f32x2 Bm = 0.5f * (ps + pd);           // mu1^2 + mu2^2
                    f32x2 S12 = 0.5f * (Es - Ed) - A;      // 2*sigma12
                    f32x2 SS  = 0.5f * (Es + Ed) - Bm;     // sigma1^2 + sigma2^2
                    f32x2 num = (A + c1) * (S12 + c2);
                    f32x2 den = (Bm + c1) * (SS + c2);
                    float sx = num.x * __builtin_amdgcn_rcpf(den.x);
                    float sy = num.y * __builtin_amdgcn_rcpf(den.y);
                    if (orow0 < HO)     lsum += sx;
                    if (orow0 + 1 < HO) lsum += sy;
                }
            }
        }

        ctx = ntx; cty = nty;
    }

    // ---------- reduction (single barrier, once per block) ----------
    #pragma unroll
    for (int off = 32; off; off >>= 1)
        lsum += __shfl_down(lsum, off, 64);
    if ((tid & 63) == 0) wsum[wv] = lsum;
    __syncthreads();
    if (tid == 0) {
        double tt = (double)wsum[0] + (double)wsum[1] +
                    (double)wsum[2] + (double)wsum[3];
        atomicAdd(acc, tt);
    }
}

__global__ void ssim_finalize(const double* __restrict__ acc,
                              float* __restrict__ out)
{
    out[0] = (float)(acc[0] / (double)(16LL * 3LL * (long long)HO * (long long)WO));
}

extern "C" void kernel_launch(void* const* d_in, const int* in_sizes, int n_in,
                              void* d_out, int out_size, void* d_ws, size_t ws_size,
                              hipStream_t stream) {
    const float* img1 = (const float*)d_in[0];
    const float* img2 = (const float*)d_in[1];
    const float* win  = (const float*)d_in[2];  // (3,1,11,11); channels identical
    float* out = (float*)d_out;
    double* acc = (double*)d_ws;

    hipMemsetAsync(acc, 0, sizeof(double), stream);

    ssim_sep_kernel<<<dim3(NBLK), 256, 0, stream>>>(img1, img2, win, acc);
    ssim_finalize<<<1, 1, 0, stream>>>(acc, out);
}